// Round 7
// baseline (2083.490 us; speedup 1.0000x reference)
//
#include <hip/hip_runtime.h>
#include <hip/hip_fp16.h>
#include <stdint.h>

#define SEQ 512
#define HIDN 512

typedef _Float16 h2_t __attribute__((ext_vector_type(2)));
typedef _Float16 h8_t __attribute__((ext_vector_type(8)));
typedef float f4_t __attribute__((ext_vector_type(4)));

__device__ __forceinline__ float fdot2f(uint32_t a, uint32_t b, float c) {
#if __has_builtin(__builtin_amdgcn_fdot2)
  return __builtin_amdgcn_fdot2(__builtin_bit_cast(h2_t, a),
                                __builtin_bit_cast(h2_t, b), c, false);
#else
  h2_t ah = __builtin_bit_cast(h2_t, a);
  h2_t bh = __builtin_bit_cast(h2_t, b);
  return c + (float)ah.x * (float)bh.x + (float)ah.y * (float)bh.y;
#endif
}

// ---------------- fp32 -> fp16 convert (contiguous) ----------------
__global__ void k_cvt(const float4* __restrict__ src, __half2* __restrict__ dst, int n4) {
  int i = blockIdx.x * blockDim.x + threadIdx.x;
  if (i < n4) {
    float4 v = src[i];
    dst[2 * i]     = __floats2half2_rn(v.x, v.y);
    dst[2 * i + 1] = __floats2half2_rn(v.z, v.w);
  }
}

// ---------------- transpose + convert: dst[c][r] = (half)src[r][c] ----------------
__global__ void k_transpose_cvt(const float* __restrict__ src, __half* __restrict__ dst,
                                int R, int C) {
  __shared__ float tile[32][33];
  int tx = threadIdx.x, ty = threadIdx.y;
  int c0 = blockIdx.x * 32, r0 = blockIdx.y * 32;
#pragma unroll
  for (int i = 0; i < 4; ++i)
    tile[ty + i * 8][tx] = src[(size_t)(r0 + ty + i * 8) * C + c0 + tx];
  __syncthreads();
#pragma unroll
  for (int i = 0; i < 4; ++i)
    dst[(size_t)(c0 + ty + i * 8) * R + r0 + tx] = __float2half(tile[tx][ty + i * 8]);
}

// ---------------- pack Wh into the k_rnn streaming layout ----------------
// Cell m (0..31) of thread t (0..1023): ks=t>>7 (K-slice), cg=t&127,
// col = cg*4 + (m>>3), sub = m&7 -> uint4 = WhT[col], pair-dwords ks*32+sub*4 ..+3.
__global__ void k_pack(const __half* __restrict__ WhT_f, const __half* __restrict__ WhT_b,
                       uint4* __restrict__ Wp_f, uint4* __restrict__ Wp_b) {
  int gid = blockIdx.x * blockDim.x + threadIdx.x;   // 0..65535
  int d = gid >> 15, r = gid & 32767, m = r >> 10, t = r & 1023;
  int cg = t & 127, ks = t >> 7, col = cg * 4 + (m >> 3), sub = m & 7;
  const __half* W = d ? WhT_b : WhT_f;
  uint4 v = ((const uint4*)(W + (size_t)col * HIDN))[ks * 8 + sub];
  (d ? Wp_b : Wp_f)[m * 1024 + t] = v;
}

// ---------------- f16 MFMA GEMM: C(MxN,f32) = A(MxK,f16) * Bt(NxK,f16)^T + bias ----------------
__global__ __launch_bounds__(256, 2) void k_gemm(
    const __half* __restrict__ A, const __half* __restrict__ Bt,
    const float* __restrict__ bias, float* __restrict__ C,
    int M, int N, int K) {
  __shared__ __align__(16) __half As[128 * 32];
  __shared__ __align__(16) __half Bs[128 * 32];
  const int tid = threadIdx.x;
  const int m0 = blockIdx.x * 128;
  const int n0 = blockIdx.y * 128;
  const int w = tid >> 6;
  const int lane = tid & 63;
  const int wm = (w >> 1) * 64;
  const int wn = (w & 1) * 64;
  const int fr = lane & 15;
  const int q = lane >> 4;
  const int lr = tid >> 2;
  const int lc = tid & 3;
  f4_t acc[4][4];
#pragma unroll
  for (int i = 0; i < 4; ++i)
#pragma unroll
    for (int jj = 0; jj < 4; ++jj) acc[i][jj] = (f4_t)(0.f);

  for (int kk = 0; kk < K; kk += 32) {
    *(uint4*)&As[lr * 32 + lc * 8]        = *(const uint4*)&A[(size_t)(m0 + lr) * K + kk + lc * 8];
    *(uint4*)&As[(64 + lr) * 32 + lc * 8] = *(const uint4*)&A[(size_t)(m0 + 64 + lr) * K + kk + lc * 8];
    *(uint4*)&Bs[lr * 32 + lc * 8]        = *(const uint4*)&Bt[(size_t)(n0 + lr) * K + kk + lc * 8];
    *(uint4*)&Bs[(64 + lr) * 32 + lc * 8] = *(const uint4*)&Bt[(size_t)(n0 + 64 + lr) * K + kk + lc * 8];
    __syncthreads();
    h8_t af[4], bf[4];
#pragma unroll
    for (int i = 0; i < 4; ++i) {
      af[i] = *(const h8_t*)&As[(wm + i * 16 + fr) * 32 + q * 8];
      bf[i] = *(const h8_t*)&Bs[(wn + i * 16 + fr) * 32 + q * 8];
    }
#pragma unroll
    for (int i = 0; i < 4; ++i)
#pragma unroll
      for (int jj = 0; jj < 4; ++jj)
        acc[i][jj] = __builtin_amdgcn_mfma_f32_16x16x32_f16(af[i], bf[jj], acc[i][jj], 0, 0, 0);
    __syncthreads();
  }
#pragma unroll
  for (int i = 0; i < 4; ++i) {
    const int row0 = m0 + wm + i * 16 + q * 4;
#pragma unroll
    for (int jj = 0; jj < 4; ++jj) {
      const int col = n0 + wn + jj * 16 + fr;
      const float bv = bias[col];
#pragma unroll
      for (int r = 0; r < 4; ++r)
        C[(size_t)(row0 + r) * N + col] = acc[i][jj][r] + bv;
    }
  }
}

// ---------------- serial recurrence: 64 blocks x 1024 threads ----------------
// Design law from rounds 2-6: the compiler will NOT keep a large weight array
// in VGPRs. So: NO register residency. Weights come from LDS (cells m<5, 80 KB)
// and a DELIBERATE per-step L2 stream (cells 5..31, pointer pinned in SGPRs so
// LICM can't hoist-then-spill). Thread (ks=t>>7, cg=t&127) does 4 columns of
// one 32-pair K-slice -> h-broadcast is 8 wave-uniform b128 (4x less than R6).
// psum[8][512] combine, 2 barriers/step.
__global__ __launch_bounds__(1024) void k_rnn(
    const uint4* __restrict__ Wp_f, const uint4* __restrict__ Wp_b,
    const float* __restrict__ A_f, const float* __restrict__ A_b,
    __half* __restrict__ bi) {
  __shared__ __align__(16) uint4 ldsw4[5 * 1024];   // 80 KB: cells m=0..4
  __shared__ __align__(16) __half hbuf[2][HIDN];    // 2 KB
  __shared__ __align__(16) float psum[8 * HIDN];    // 16 KB
  const int t = threadIdx.x;
  const int ks = t >> 7;            // K-slice 0..7 (wave-uniform: 2 waves per slice)
  const int cg = t & 127;           // column group -> cols cg*4 .. cg*4+3
  const int d = blockIdx.x & 1;
  const int b = blockIdx.x >> 1;
  const uint4* Wp = d ? Wp_b : Wp_f;
  const float* A = (d ? A_b : A_f) + (size_t)b * SEQ * HIDN;

#pragma unroll
  for (int m = 0; m < 5; ++m) ldsw4[m * 1024 + t] = Wp[m * 1024 + t];
  if (t < HIDN) hbuf[0][t] = __float2half(0.f);
  __syncthreads();

  // Opaque pointer: mutated by empty asm each iteration so the 27 streamed
  // loads can never be hoisted out of the loop (and thus never spilled).
  const char* wp = (const char*)Wp;

  const int tstep = d ? -1 : 1;
  int tt = d ? (SEQ - 1) : 0;
  float a_next = (t < HIDN) ? A[(size_t)tt * HIDN + t] : 0.f;
  int cur = 0;
  for (int s = 0; s < SEQ; ++s) {
    asm volatile("" : "+s"(wp));
    // ---- phase A: partial dots ----
    const uint4* hp = (const uint4*)hbuf[cur] + (ks << 3);  // wave-uniform base
    uint4 hv[8];
#pragma unroll
    for (int u = 0; u < 8; ++u) hv[u] = hp[u];              // broadcast b128 reads
    float acc[4] = {0.f, 0.f, 0.f, 0.f};
#pragma unroll
    for (int m = 0; m < 32; ++m) {
      const int ci = m >> 3, sub = m & 7;
      uint4 w;
      if (m < 5) w = ldsw4[m * 1024 + t];
      else       w = *(const uint4*)(wp + (((size_t)m * 1024 + t) << 4));
      acc[ci] = fdot2f(hv[sub].x, w.x, acc[ci]);
      acc[ci] = fdot2f(hv[sub].y, w.y, acc[ci]);
      acc[ci] = fdot2f(hv[sub].z, w.z, acc[ci]);
      acc[ci] = fdot2f(hv[sub].w, w.w, acc[ci]);
    }
    *(f4_t*)&psum[ks * HIDN + cg * 4] = (f4_t){acc[0], acc[1], acc[2], acc[3]};
    __syncthreads();
    // ---- phase B: combine + tanh + publish (waves 0..7) ----
    if (t < HIDN) {
      float a_cur = a_next;
      float p = a_cur +
          ((psum[t] + psum[HIDN + t]) + (psum[2 * HIDN + t] + psum[3 * HIDN + t])) +
          ((psum[4 * HIDN + t] + psum[5 * HIDN + t]) + (psum[6 * HIDN + t] + psum[7 * HIDN + t]));
      float ap = fabsf(p);
      float e = __expf(2.f * ap);
      float th = 1.f - 2.f * __builtin_amdgcn_rcpf(e + 1.f);  // tanh(|p|)
      float h = copysignf(th, p);
      __half hh = __float2half(h);
      hbuf[cur ^ 1][t] = hh;
      bi[(size_t)b * SEQ * 1024 + (size_t)tt * 1024 + d * HIDN + t] = hh;
      int tn = tt + tstep;
      tn = tn < 0 ? 0 : (tn > SEQ - 1 ? SEQ - 1 : tn);
      a_next = A[(size_t)tn * HIDN + t];    // prefetch next step
    }
    cur ^= 1;
    tt += tstep;
    __syncthreads();
  }
}

extern "C" void kernel_launch(void* const* d_in, const int* in_sizes, int n_in,
                              void* d_out, int out_size, void* d_ws, size_t ws_size,
                              hipStream_t stream) {
  const float* input_seq = (const float*)d_in[0];  // (32,512,512)
  const float* W_f = (const float*)d_in[1];        // (1024,512)
  const float* b_f = (const float*)d_in[2];
  const float* W_b = (const float*)d_in[3];
  const float* b_b = (const float*)d_in[4];
  const float* W_o = (const float*)d_in[5];        // (1024,512)
  const float* b_o = (const float*)d_in[6];
  float* out = (float*)d_out;

  char* ws = (char*)d_ws;
  __half* Xh    = (__half*)(ws);                    // 16 MB  (16384x512 f16)
  float*  A_f   = (float*)(ws + 16777216);          // 32 MB
  float*  A_b   = (float*)(ws + 50331648);          // 32 MB
  __half* bi    = (__half*)(ws + 83886080);         // 32 MB  (16384x1024 f16)
  __half* WxT_f = (__half*)(ws + 117440512);        // 512 KB
  __half* WxT_b = (__half*)(ws + 117964800);
  __half* WhT_f = (__half*)(ws + 118489088);        // 512 KB
  __half* WhT_b = (__half*)(ws + 119013376);
  __half* WoT   = (__half*)(ws + 119537664);        // 1 MB   (512x1024, [o][c])
  uint4*  Wp_f  = (uint4*)(ws + 120586240);         // 512 KB packed stream layout
  uint4*  Wp_b  = (uint4*)(ws + 121110528);         // 512 KB

  k_cvt<<<8192, 256, 0, stream>>>((const float4*)input_seq, (__half2*)Xh, 2097152);
  dim3 tb(32, 8);
  k_transpose_cvt<<<dim3(16, 16), tb, 0, stream>>>(W_f,          WxT_f, 512, 512);
  k_transpose_cvt<<<dim3(16, 16), tb, 0, stream>>>(W_f + 262144, WhT_f, 512, 512);
  k_transpose_cvt<<<dim3(16, 16), tb, 0, stream>>>(W_b,          WxT_b, 512, 512);
  k_transpose_cvt<<<dim3(16, 16), tb, 0, stream>>>(W_b + 262144, WhT_b, 512, 512);
  k_transpose_cvt<<<dim3(16, 32), tb, 0, stream>>>(W_o,          WoT, 1024, 512);
  k_pack<<<256, 256, 0, stream>>>(WhT_f, WhT_b, Wp_f, Wp_b);

  k_gemm<<<dim3(128, 4), 256, 0, stream>>>(Xh, WxT_f, b_f, A_f, 16384, 512, 512);
  k_gemm<<<dim3(128, 4), 256, 0, stream>>>(Xh, WxT_b, b_b, A_b, 16384, 512, 512);

  k_rnn<<<64, 1024, 0, stream>>>(Wp_f, Wp_b, A_f, A_b, bi);

  k_gemm<<<dim3(128, 4), 256, 0, stream>>>(bi, WoT, b_o, out, 16384, 512, 1024);
}